// Round 7
// baseline (195.858 us; speedup 1.0000x reference)
//
#include <hip/hip_runtime.h>
#include <hip/hip_bf16.h>
#include <math.h>

#define B_N 4096
#define D_N 768
#define C_N 10

typedef short bf16x8 __attribute__((ext_vector_type(8)));
typedef float f32x4 __attribute__((ext_vector_type(4)));

// ws layout (floats):
//   [0] ce_sum   [1] taml_sum
//   [8..18)   counts[10]
//   [32..32+7680)  class sums [10][768]
// byte offset 65536: enorm bf16 [4096*768]  (6291456 bytes)

static __device__ __forceinline__ unsigned short bf16bits(float f, float s) {
    __hip_bfloat16 h = __float2bfloat16(f * s);
    return *(unsigned short*)&h;
}

// ---------------- merged prep: CE + histogram | class sums | row-normalize ----------------
// blocks [0,16): CE; [16,208): class segment sums; [208,1232): enorm (wave/row)
__global__ void k_prep(const float* __restrict__ logits,
                       const int* __restrict__ labels,
                       const float* __restrict__ emb,
                       float* __restrict__ ws,
                       __hip_bfloat16* __restrict__ enorm) {
    __shared__ float red[256];
    __shared__ float cnt[C_N];
    int bb = blockIdx.x;
    int t = threadIdx.x;

    if (bb < 16) {
        if (t < C_N) cnt[t] = 0.f;
        __syncthreads();
        int row = bb * 256 + t;
        int lab = labels[row];
        const float* lp = logits + (size_t)row * C_N;
        float m = lp[0];
#pragma unroll
        for (int c = 1; c < C_N; ++c) m = fmaxf(m, lp[c]);
        float s = 0.f;
#pragma unroll
        for (int c = 0; c < C_N; ++c) s += __expf(lp[c] - m);
        float val = (m + __logf(s)) - lp[lab];
        atomicAdd(&cnt[lab], 1.0f);
        red[t] = val;
        __syncthreads();
        for (int off = 128; off; off >>= 1) {
            if (t < off) red[t] += red[t + off];
            __syncthreads();
        }
        if (t == 0) atomicAdd(&ws[0], red[0]);
        if (t < C_N) atomicAdd(&ws[8 + t], cnt[t]);
    } else if (bb < 208) {
        int bx = (bb - 16) % 3, by = (bb - 16) / 3;
        int col = bx * 256 + t;
        int rbase = by * 64;
        float a[C_N];
#pragma unroll
        for (int c = 0; c < C_N; ++c) a[c] = 0.f;
        const float* p = emb + (size_t)rbase * D_N + col;
#pragma unroll 4
        for (int rr = 0; rr < 64; ++rr) {
            int lab = labels[rbase + rr];
            float v = p[(size_t)rr * D_N];
#pragma unroll
            for (int c = 0; c < C_N; ++c) a[c] += (lab == c) ? v : 0.f;
        }
        float* sums = ws + 32;
#pragma unroll
        for (int c = 0; c < C_N; ++c) atomicAdd(&sums[c * D_N + col], a[c]);
    } else {
        int w = t >> 6, lane = t & 63;
        int row = (bb - 208) * 4 + w;
        const float4* src = (const float4*)(emb + (size_t)row * D_N);
        float4 x0 = src[lane];
        float4 x1 = src[lane + 64];
        float4 x2 = src[lane + 128];
        float ss = x0.x * x0.x + x0.y * x0.y + x0.z * x0.z + x0.w * x0.w
                 + x1.x * x1.x + x1.y * x1.y + x1.z * x1.z + x1.w * x1.w
                 + x2.x * x2.x + x2.y * x2.y + x2.z * x2.z + x2.w * x2.w;
#pragma unroll
        for (int off = 32; off; off >>= 1) ss += __shfl_xor(ss, off, 64);
        float inv = 1.0f / fmaxf(sqrtf(ss), 1e-12f);
        ushort4* dst = (ushort4*)(enorm + (size_t)row * D_N);
        ushort4 u0, u1, u2;
        u0.x = bf16bits(x0.x, inv); u0.y = bf16bits(x0.y, inv);
        u0.z = bf16bits(x0.z, inv); u0.w = bf16bits(x0.w, inv);
        u1.x = bf16bits(x1.x, inv); u1.y = bf16bits(x1.y, inv);
        u1.z = bf16bits(x1.z, inv); u1.w = bf16bits(x1.w, inv);
        u2.x = bf16bits(x2.x, inv); u2.y = bf16bits(x2.y, inv);
        u2.z = bf16bits(x2.z, inv); u2.w = bf16bits(x2.w, inv);
        dst[lane]       = u0;
        dst[lane + 64]  = u1;
        dst[lane + 128] = u2;
    }
}

// ---------------- fused TAML GEMM: no LDS staging, no K-loop barriers ----------------
// 128x128 tile / block, 4 waves (2x2), each wave a 64x64 tile via 4x4 of 16x16x32.
// Fragments loaded DIRECTLY from global (L2-resident: E = 6.3 MB). For a Gram
// matrix A- and B-operand fragments have the same row-major layout:
// lane(m16,quad) <- 16B at E[row(m16)] [k0 + quad*8 .. +7].
__global__ __launch_bounds__(256) void k_taml(const __hip_bfloat16* __restrict__ E,
                                              const int* __restrict__ labels,
                                              const float* __restrict__ topo,
                                              float* __restrict__ ws) {
    int bi = blockIdx.y, bj = blockIdx.x;
    if (bj < bi) return;   // uniform exit, before any barrier

    __shared__ int lA[128], lB[128];
    __shared__ float topo_s[C_N * C_N];
    __shared__ float wsum[4];

    int t = threadIdx.x;
    int ib0 = bi * 128, jb0 = bj * 128;
    if (t < 128) lA[t] = labels[ib0 + t];
    else         lB[t - 128] = labels[jb0 + t - 128];
    if (t < C_N * C_N) topo_s[t] = topo[t];
    __syncthreads();   // labels/topo visible; the ONLY pre-epilogue barrier

    int w = t >> 6, lane = t & 63;
    int quad = lane >> 4, m16 = lane & 15;
    int wrow = (w >> 1) * 64, wcol = (w & 1) * 64;

    // per-lane fragment base pointers (16B strided by 64B per K-step)
    const bf16x8* pa[4];
    const bf16x8* pb[4];
#pragma unroll
    for (int x = 0; x < 4; ++x) {
        pa[x] = (const bf16x8*)(E + (size_t)(ib0 + wrow + x * 16 + m16) * D_N + quad * 8);
        pb[x] = (const bf16x8*)(E + (size_t)(jb0 + wcol + x * 16 + m16) * D_N + quad * 8);
    }

    f32x4 acc[4][4];
    f32x4 z = {0.f, 0.f, 0.f, 0.f};
#pragma unroll
    for (int mt = 0; mt < 4; ++mt)
#pragma unroll
        for (int nt = 0; nt < 4; ++nt) acc[mt][nt] = z;

#pragma unroll 2
    for (int k = 0; k < 24; ++k) {         // K = 768 = 24 * 32
        bf16x8 af[4], bfr[4];
#pragma unroll
        for (int x = 0; x < 4; ++x) {
            af[x]  = pa[x][k * 4];          // k*4 * 16B = 64B = 32 elems
            bfr[x] = pb[x][k * 4];
        }
#pragma unroll
        for (int mt = 0; mt < 4; ++mt)
#pragma unroll
            for (int nt = 0; nt < 4; ++nt)
                acc[mt][nt] = __builtin_amdgcn_mfma_f32_16x16x32_bf16(
                    af[mt], bfr[nt], acc[mt][nt], 0, 0, 0);
    }

    // epilogue: relu(sim - 1 + margin) over valid (li!=lj) upper-tri pairs, x2
    float local = 0.f;
#pragma unroll
    for (int mt = 0; mt < 4; ++mt) {
#pragma unroll
        for (int nt = 0; nt < 4; ++nt) {
#pragma unroll
            for (int reg = 0; reg < 4; ++reg) {
                int il = wrow + mt * 16 + quad * 4 + reg;
                int jl = wcol + nt * 16 + m16;
                int gi = ib0 + il, gj = jb0 + jl;
                int li = lA[il], lj = lB[jl];
                float v = acc[mt][nt][reg] - 1.0f + topo_s[li * C_N + lj];
                if (li != lj && gi < gj && v > 0.f) local += v;
            }
        }
    }
    local *= 2.0f;

#pragma unroll
    for (int off = 32; off; off >>= 1) local += __shfl_down(local, off, 64);
    if (lane == 0) wsum[w] = local;
    __syncthreads();
    if (t == 0) atomicAdd(&ws[1], wsum[0] + wsum[1] + wsum[2] + wsum[3]);
}

// ---------------- TALS + nvalid + final combine ----------------
__global__ void k_tals(const float* __restrict__ topo, float* __restrict__ ws,
                       float* __restrict__ out) {
    __shared__ float cents[C_N * D_N];   // 30 KB
    __shared__ float ed[112];
    __shared__ float cnt_s[C_N];
    int t = threadIdx.x;   // 256 threads = 4 waves
    int w = t >> 6, lane = t & 63;
    const float* counts = ws + 8;
    const float* sums = ws + 32;
    if (t < C_N) cnt_s[t] = counts[t];
    __syncthreads();
    for (int idx = t; idx < C_N * D_N; idx += 256) {
        int c = idx / D_N;
        cents[idx] = sums[idx] / fmaxf(cnt_s[c], 1.0f);
    }
    __syncthreads();
    for (int pp = 0; pp < 25; ++pp) {   // 100 pairs; wave w: 25w..25w+24
        int p = w * 25 + pp;
        int i = p / C_N, j = p - (p / C_N) * C_N;
        const float* ci = cents + i * D_N;
        const float* cj = cents + j * D_N;
        float s = 0.f;
        for (int d = lane; d < D_N; d += 64) {
            float diff = ci[d] - cj[d];
            s += diff * diff;
        }
#pragma unroll
        for (int off = 32; off; off >>= 1) s += __shfl_xor(s, off, 64);
        if (lane == 0) ed[p] = sqrtf(s + 1e-12f);
    }
    __syncthreads();
    if (w == 0) {
        float e0 = ed[lane];
        float e1 = (lane < 36) ? ed[lane + 64] : 0.f;
        float mx = fmaxf(e0, e1);
#pragma unroll
        for (int off = 32; off; off >>= 1) mx = fmaxf(mx, __shfl_xor(mx, off, 64));
        float inv = 1.0f / (mx + 1e-8f);
        float d0 = e0 * inv - topo[lane];
        float s = d0 * d0;
        if (lane < 36) {
            float d1 = e1 * inv - topo[lane + 64];
            s += d1 * d1;
        }
#pragma unroll
        for (int off = 32; off; off >>= 1) s += __shfl_xor(s, off, 64);
        if (lane == 0) {
            float tals = s * (1.0f / (C_N * C_N));
            float s2 = 0.f;
#pragma unroll
            for (int c = 0; c < C_N; ++c) s2 += cnt_s[c] * cnt_s[c];
            float nvalid = (float)B_N * (float)B_N - s2;
            float ce   = ws[0] / (float)B_N;
            float taml = ws[1] / fmaxf(nvalid, 1.0f);
            out[0] = ce + 0.5f * tals + 0.5f * taml;
            out[1] = ce;
            out[2] = tals;
            out[3] = taml;
        }
    }
}

extern "C" void kernel_launch(void* const* d_in, const int* in_sizes, int n_in,
                              void* d_out, int out_size, void* d_ws, size_t ws_size,
                              hipStream_t stream) {
    const float* logits = (const float*)d_in[0];
    const int*   labels = (const int*)d_in[1];
    const float* emb    = (const float*)d_in[2];
    const float* topo   = (const float*)d_in[3];
    float* ws = (float*)d_ws;
    __hip_bfloat16* enorm = (__hip_bfloat16*)((char*)d_ws + 65536);
    float* out = (float*)d_out;

    hipMemsetAsync(d_ws, 0, 31232, stream);
    k_prep<<<1232, 256, 0, stream>>>(logits, labels, emb, ws, enorm);
    k_taml<<<dim3(32, 32), 256, 0, stream>>>(enorm, labels, topo, ws);
    k_tals<<<1, 256, 0, stream>>>(topo, ws, out);
}

// Round 8
// 136.601 us; speedup vs baseline: 1.4338x; 1.4338x over previous
//
#include <hip/hip_runtime.h>
#include <hip/hip_bf16.h>
#include <math.h>

#define B_N 4096
#define D_N 768
#define C_N 10

typedef short bf16x8 __attribute__((ext_vector_type(8)));
typedef float f32x4 __attribute__((ext_vector_type(4)));

// ws layout (floats):
//   [0] ce_sum   [1] taml_sum
//   [8..18)   counts[10]
//   [32..32+7680)  class sums [10][768]
// byte offset 65536: enorm bf16 [4096*768]  (6291456 bytes)

typedef __attribute__((address_space(1))) const void gvoid;
typedef __attribute__((address_space(3))) void lvoid;

static __device__ __forceinline__ void gl2lds16(const void* g, void* l) {
    // async global->LDS, 16B per lane, dest = l + lane*16 (wave-uniform l)
    __builtin_amdgcn_global_load_lds((gvoid*)g, (lvoid*)l, 16, 0, 0);
}

static __device__ __forceinline__ unsigned short bf16bits(float f, float s) {
    __hip_bfloat16 h = __float2bfloat16(f * s);
    return *(unsigned short*)&h;
}

// ---------------- merged prep: CE + histogram | class sums | row-normalize ----------------
// blocks [0,16): CE; [16,208): class segment sums; [208,1232): enorm (wave/row)
__global__ void k_prep(const float* __restrict__ logits,
                       const int* __restrict__ labels,
                       const float* __restrict__ emb,
                       float* __restrict__ ws,
                       __hip_bfloat16* __restrict__ enorm) {
    __shared__ float red[256];
    __shared__ float cnt[C_N];
    int bb = blockIdx.x;
    int t = threadIdx.x;

    if (bb < 16) {
        if (t < C_N) cnt[t] = 0.f;
        __syncthreads();
        int row = bb * 256 + t;
        int lab = labels[row];
        const float* lp = logits + (size_t)row * C_N;
        float m = lp[0];
#pragma unroll
        for (int c = 1; c < C_N; ++c) m = fmaxf(m, lp[c]);
        float s = 0.f;
#pragma unroll
        for (int c = 0; c < C_N; ++c) s += __expf(lp[c] - m);
        float val = (m + __logf(s)) - lp[lab];
        atomicAdd(&cnt[lab], 1.0f);
        red[t] = val;
        __syncthreads();
        for (int off = 128; off; off >>= 1) {
            if (t < off) red[t] += red[t + off];
            __syncthreads();
        }
        if (t == 0) atomicAdd(&ws[0], red[0]);
        if (t < C_N) atomicAdd(&ws[8 + t], cnt[t]);
    } else if (bb < 208) {
        int bx = (bb - 16) % 3, by = (bb - 16) / 3;
        int col = bx * 256 + t;
        int rbase = by * 64;
        float a[C_N];
#pragma unroll
        for (int c = 0; c < C_N; ++c) a[c] = 0.f;
        const float* p = emb + (size_t)rbase * D_N + col;
#pragma unroll 4
        for (int rr = 0; rr < 64; ++rr) {
            int lab = labels[rbase + rr];
            float v = p[(size_t)rr * D_N];
#pragma unroll
            for (int c = 0; c < C_N; ++c) a[c] += (lab == c) ? v : 0.f;
        }
        float* sums = ws + 32;
#pragma unroll
        for (int c = 0; c < C_N; ++c) atomicAdd(&sums[c * D_N + col], a[c]);
    } else {
        int w = t >> 6, lane = t & 63;
        int row = (bb - 208) * 4 + w;
        const float4* src = (const float4*)(emb + (size_t)row * D_N);
        float4 x0 = src[lane];
        float4 x1 = src[lane + 64];
        float4 x2 = src[lane + 128];
        float ss = x0.x * x0.x + x0.y * x0.y + x0.z * x0.z + x0.w * x0.w
                 + x1.x * x1.x + x1.y * x1.y + x1.z * x1.z + x1.w * x1.w
                 + x2.x * x2.x + x2.y * x2.y + x2.z * x2.z + x2.w * x2.w;
#pragma unroll
        for (int off = 32; off; off >>= 1) ss += __shfl_xor(ss, off, 64);
        float inv = 1.0f / fmaxf(sqrtf(ss), 1e-12f);
        ushort4* dst = (ushort4*)(enorm + (size_t)row * D_N);
        ushort4 u0, u1, u2;
        u0.x = bf16bits(x0.x, inv); u0.y = bf16bits(x0.y, inv);
        u0.z = bf16bits(x0.z, inv); u0.w = bf16bits(x0.w, inv);
        u1.x = bf16bits(x1.x, inv); u1.y = bf16bits(x1.y, inv);
        u1.z = bf16bits(x1.z, inv); u1.w = bf16bits(x1.w, inv);
        u2.x = bf16bits(x2.x, inv); u2.y = bf16bits(x2.y, inv);
        u2.z = bf16bits(x2.z, inv); u2.w = bf16bits(x2.w, inv);
        dst[lane]       = u0;
        dst[lane + 64]  = u1;
        dst[lane + 128] = u2;
    }
}

// ---------------- fused TAML GEMM ----------------
// 128x128 tile, BK=64, double-buffered LDS, async global_load_lds (16B),
// ONE barrier per K-iter placed AFTER compute so the pre-barrier vmcnt(0)
// drain of next-tile loads is covered by this iteration's 32 MFMAs.
// 3-bit XOR k-slot swizzle: fragment ds_read_b128 = 2 lanes/bank (free).
__global__ __launch_bounds__(256) void k_taml(const __hip_bfloat16* __restrict__ E,
                                              const int* __restrict__ labels,
                                              const float* __restrict__ topo,
                                              float* __restrict__ ws) {
    int bi = blockIdx.y, bj = blockIdx.x;
    if (bj < bi) return;   // uniform exit, before any barrier

    __shared__ __align__(16) __hip_bfloat16 As[2][128 * 64];   // 2 x 16 KB
    __shared__ __align__(16) __hip_bfloat16 Bs[2][128 * 64];   // 2 x 16 KB
    __shared__ int lA[128], lB[128];
    __shared__ float topo_s[C_N * C_N];
    __shared__ float wsum[4];

    int t = threadIdx.x;
    int ib0 = bi * 128, jb0 = bj * 128;
    if (t < 128) lA[t] = labels[ib0 + t];
    else         lB[t - 128] = labels[jb0 + t - 128];
    if (t < C_N * C_N) topo_s[t] = topo[t];

    int w = t >> 6, lane = t & 63;
    int quad = lane >> 4, m16 = lane & 15;
    int wrow = (w >> 1) * 64, wcol = (w & 1) * 64;

    f32x4 acc[4][4];
    f32x4 z = {0.f, 0.f, 0.f, 0.f};
#pragma unroll
    for (int mt = 0; mt < 4; ++mt)
#pragma unroll
        for (int nt = 0; nt < 4; ++nt) acc[mt][nt] = z;

    // staging: 16 chunks of 1KB per tile (chunk h = rows 8h..8h+7, full 64-elem rows).
    // wave w owns chunks {w, w+4, w+8, w+12}. lane: r = lane>>3 (row in chunk),
    // c = lane&7 (16B k-slot); lane fetches global slot c^r -> LDS slot c swizzled.
    int rl = lane >> 3, cs = lane & 7;
    int csw = (cs ^ rl) * 8;   // elems
    const __hip_bfloat16* gA[4];
    const __hip_bfloat16* gB[4];
    int ldsoff[4];
#pragma unroll
    for (int h = 0; h < 4; ++h) {
        int chunk = w + 4 * h;
        gA[h] = E + (size_t)(ib0 + chunk * 8 + rl) * D_N + csw;
        gB[h] = E + (size_t)(jb0 + chunk * 8 + rl) * D_N + csw;
        ldsoff[h] = chunk * 512;   // elems (1 KB per chunk)
    }

    // prologue: tile 0 -> buffer 0
#pragma unroll
    for (int h = 0; h < 4; ++h) {
        gl2lds16(gA[h], &As[0][ldsoff[h]]);
        gl2lds16(gB[h], &Bs[0][ldsoff[h]]);
    }
    __syncthreads();   // drain tile0 (full latency paid once); also covers lA/lB/topo_s

    for (int kt = 0; kt < 12; ++kt) {
        int cur = kt & 1, nxt = cur ^ 1;
        if (kt < 11) {
#pragma unroll
            for (int h = 0; h < 4; ++h) {
                gl2lds16(gA[h] + (kt + 1) * 64, &As[nxt][ldsoff[h]]);
                gl2lds16(gB[h] + (kt + 1) * 64, &Bs[nxt][ldsoff[h]]);
            }
        }
#pragma unroll
        for (int ks = 0; ks < 2; ++ks) {
            bf16x8 af[4], bfr[4];
#pragma unroll
            for (int x = 0; x < 4; ++x) {
                int rowA = wrow + x * 16 + m16;
                int rowB = wcol + x * 16 + m16;
                int slot = ks * 4 + quad;
                af[x]  = *(const bf16x8*)(&As[cur][rowA * 64 + ((slot ^ (rowA & 7)) * 8)]);
                bfr[x] = *(const bf16x8*)(&Bs[cur][rowB * 64 + ((slot ^ (rowB & 7)) * 8)]);
            }
#pragma unroll
            for (int mt = 0; mt < 4; ++mt)
#pragma unroll
                for (int nt = 0; nt < 4; ++nt)
                    acc[mt][nt] = __builtin_amdgcn_mfma_f32_16x16x32_bf16(
                        af[mt], bfr[nt], acc[mt][nt], 0, 0, 0);
        }
        __syncthreads();   // drain of next-tile loads happens AFTER compute
    }

    // epilogue: relu(sim - 1 + margin) over valid (li!=lj) upper-tri pairs, x2
    float local = 0.f;
#pragma unroll
    for (int mt = 0; mt < 4; ++mt) {
#pragma unroll
        for (int nt = 0; nt < 4; ++nt) {
#pragma unroll
            for (int reg = 0; reg < 4; ++reg) {
                int il = wrow + mt * 16 + quad * 4 + reg;
                int jl = wcol + nt * 16 + m16;
                int gi = ib0 + il, gj = jb0 + jl;
                int li = lA[il], lj = lB[jl];
                float v = acc[mt][nt][reg] - 1.0f + topo_s[li * C_N + lj];
                if (li != lj && gi < gj && v > 0.f) local += v;
            }
        }
    }
    local *= 2.0f;

#pragma unroll
    for (int off = 32; off; off >>= 1) local += __shfl_down(local, off, 64);
    if (lane == 0) wsum[w] = local;
    __syncthreads();
    if (t == 0) atomicAdd(&ws[1], wsum[0] + wsum[1] + wsum[2] + wsum[3]);
}

// ---------------- TALS + nvalid + final combine ----------------
__global__ void k_tals(const float* __restrict__ topo, float* __restrict__ ws,
                       float* __restrict__ out) {
    __shared__ float cents[C_N * D_N];   // 30 KB
    __shared__ float ed[112];
    __shared__ float cnt_s[C_N];
    int t = threadIdx.x;   // 256 threads = 4 waves
    int w = t >> 6, lane = t & 63;
    const float* counts = ws + 8;
    const float* sums = ws + 32;
    if (t < C_N) cnt_s[t] = counts[t];
    __syncthreads();
    for (int idx = t; idx < C_N * D_N; idx += 256) {
        int c = idx / D_N;
        cents[idx] = sums[idx] / fmaxf(cnt_s[c], 1.0f);
    }
    __syncthreads();
    for (int pp = 0; pp < 25; ++pp) {   // 100 pairs; wave w: 25w..25w+24
        int p = w * 25 + pp;
        int i = p / C_N, j = p - (p / C_N) * C_N;
        const float* ci = cents + i * D_N;
        const float* cj = cents + j * D_N;
        float s = 0.f;
        for (int d = lane; d < D_N; d += 64) {
            float diff = ci[d] - cj[d];
            s += diff * diff;
        }
#pragma unroll
        for (int off = 32; off; off >>= 1) s += __shfl_xor(s, off, 64);
        if (lane == 0) ed[p] = sqrtf(s + 1e-12f);
    }
    __syncthreads();
    if (w == 0) {
        float e0 = ed[lane];
        float e1 = (lane < 36) ? ed[lane + 64] : 0.f;
        float mx = fmaxf(e0, e1);
#pragma unroll
        for (int off = 32; off; off >>= 1) mx = fmaxf(mx, __shfl_xor(mx, off, 64));
        float inv = 1.0f / (mx + 1e-8f);
        float d0 = e0 * inv - topo[lane];
        float s = d0 * d0;
        if (lane < 36) {
            float d1 = e1 * inv - topo[lane + 64];
            s += d1 * d1;
        }
#pragma unroll
        for (int off = 32; off; off >>= 1) s += __shfl_xor(s, off, 64);
        if (lane == 0) {
            float tals = s * (1.0f / (C_N * C_N));
            float s2 = 0.f;
#pragma unroll
            for (int c = 0; c < C_N; ++c) s2 += cnt_s[c] * cnt_s[c];
            float nvalid = (float)B_N * (float)B_N - s2;
            float ce   = ws[0] / (float)B_N;
            float taml = ws[1] / fmaxf(nvalid, 1.0f);
            out[0] = ce + 0.5f * tals + 0.5f * taml;
            out[1] = ce;
            out[2] = tals;
            out[3] = taml;
        }
    }
}

extern "C" void kernel_launch(void* const* d_in, const int* in_sizes, int n_in,
                              void* d_out, int out_size, void* d_ws, size_t ws_size,
                              hipStream_t stream) {
    const float* logits = (const float*)d_in[0];
    const int*   labels = (const int*)d_in[1];
    const float* emb    = (const float*)d_in[2];
    const float* topo   = (const float*)d_in[3];
    float* ws = (float*)d_ws;
    __hip_bfloat16* enorm = (__hip_bfloat16*)((char*)d_ws + 65536);
    float* out = (float*)d_out;

    hipMemsetAsync(d_ws, 0, 31232, stream);
    k_prep<<<1232, 256, 0, stream>>>(logits, labels, emb, ws, enorm);
    k_taml<<<dim3(32, 32), 256, 0, stream>>>(enorm, labels, topo, ws);
    k_tals<<<1, 256, 0, stream>>>(topo, ws, out);
}